// Round 1
// 192.668 us; speedup vs baseline: 1.0281x; 1.0281x over previous
//
#include <hip/hip_runtime.h>
#include <hip/hip_bf16.h>

// MicroHeadAttention on MI355X (gfx950). fp32 in / fp32 out, bf16 MFMA internally.
// Pipeline: [cvt fp32->bf16] -> [QKV gemm 256x256 8-phase] -> [transpose_v]
//        -> [attn v10] -> [out-proj gemm 128x64].
// Packed index i = n*8 + m per (b,g): scrambled head m'=i>>11, pos = i&2047.
// Address of packed row i: (b*2048 + (i>>3))*1024 + g*512 + (i&7)*64.
// Workspace (32 MB): Wb(8) | xb(8, reused as VT) | Qb(8, reused as Cb) | Kb(8).
// V uses d_out as scratch (dead before out-proj overwrites d_out).

typedef unsigned short ushortT;
typedef __attribute__((ext_vector_type(8))) short short8;
typedef __attribute__((ext_vector_type(4))) float floatx4;

__device__ inline float bf2f(ushortT u) {
    union { unsigned int i; float f; } v; v.i = ((unsigned int)u) << 16; return v.f;
}
__device__ inline ushortT f2bf(float f) {
    union { float f; unsigned int i; } v; v.f = f;
    unsigned int x = v.i;
    return (ushortT)((x + 0x7fffu + ((x >> 16) & 1u)) >> 16);  // RNE
}

__device__ inline void gl_lds16(const ushortT* g, ushortT* lds) {
    __builtin_amdgcn_global_load_lds(
        (const __attribute__((address_space(1))) unsigned int*)g,
        (__attribute__((address_space(3))) unsigned int*)lds, 16, 0, 0);
}

// ---------------------------------------------------------------------------
// cvt: x (4M f32) -> xb bf16; Wq,Wk,Wv,Wo (1M each) -> Wb stacked bf16.
// ---------------------------------------------------------------------------
__global__ __launch_bounds__(256) void cvt_bf16(
    const float* __restrict__ x,
    const float* __restrict__ Wq, const float* __restrict__ Wk,
    const float* __restrict__ Wv, const float* __restrict__ Wo,
    ushortT* __restrict__ xb, ushortT* __restrict__ Wb)
{
    const unsigned tid = blockIdx.x * 256 + threadIdx.x;
    const size_t e = (size_t)tid * 8;
    const float* src;
    ushortT* dst;
    size_t off;
    if (e < (size_t)(4u << 20)) { src = x; dst = xb; off = e; }
    else {
        const size_t r = e - (size_t)(4u << 20);
        const int wsel = (int)(r >> 20);
        off = r & 0xFFFFFu;
        src = (wsel == 0) ? Wq : (wsel == 1) ? Wk : (wsel == 2) ? Wv : Wo;
        dst = Wb + ((size_t)wsel << 20);
    }
    const float4 f0 = ((const float4*)(src + off))[0];
    const float4 f1 = ((const float4*)(src + off))[1];
    union { __hip_bfloat162 h[4]; uint4 u; } pk;
    pk.h[0] = __float22bfloat162_rn(float2{f0.x, f0.y});
    pk.h[1] = __float22bfloat162_rn(float2{f0.z, f0.w});
    pk.h[2] = __float22bfloat162_rn(float2{f1.x, f1.y});
    pk.h[3] = __float22bfloat162_rn(float2{f1.z, f1.w});
    *(uint4*)(dst + off) = pk.u;
}

// ---------------------------------------------------------------------------
// gemm_qkv_8p: C[m,n] = sum_k A[m,k]*W[n,k] + bias[n], bf16 out.
// 256x256 tile, BK=64, 512 thr (8 waves 2Mx4N, 128x64 per wave), 16 K-tiles.
// T3+T4+T5 schedule: raw s_barrier (no vmcnt drain) + counted vmcnt(8) +
// setprio around MFMA clusters. 128 KB LDS: A0|B0|A1|B1 (16384 elts each),
// XOR chunk swizzle (pre-swizzled global source, linear gl_lds dest).
//
// Staging ledger (race-free by construction):
//   tile t -> buf[t&1]. issue8(tile) = 8 gl_lds16/thread. Issue points:
//   prologue: t0->buf0, t1->buf1.  loop it: after GROUP(buf0): t_{2it+2}->buf0;
//   after GROUP(buf1): t_{2it+3}->buf1.  Each issue targets the buffer whose
//   last reader group just closed (final phase barrier => all waves' ds_reads
//   done), and the staged buffer is idle for the following group.
//   vmcnt(8)+barrier before each group => oldest 8 loads (the tile about to
//   be read, issued 4 phases earlier) landed; 8 loads stay in flight.
//   vmcnt(0) only in the epilogue group.
// Per phase: 4-or-8 ds_read_b128, barrier, 16 MFMA (setprio), barrier.
// W-frags per ks reused across the two m-half phases (24 reads/tile/wave).
// ---------------------------------------------------------------------------
__global__ __launch_bounds__(512, 2) void gemm_qkv_8p(
    const ushortT* __restrict__ A, const ushortT* __restrict__ Wst,
    const float* __restrict__ b0, const float* __restrict__ b1, const float* __restrict__ b2,
    ushortT* __restrict__ O0, ushortT* __restrict__ O1, ushortT* __restrict__ O2)
{
    __shared__ __align__(16) ushortT sm[65536];   // 128 KB

    const int t = threadIdx.x;
    const int bid = blockIdx.x;                    // 0..191
    const int wg = (bid & 7) * 24 + (bid >> 3);    // bijective XCD chunk swizzle
    const int mt = wg / 12;                        // 0..15
    const int nt = wg - mt * 12;                   // 0..11 (3 mats x 4 tiles)
    const int m0 = mt * 256;
    const int mat = nt >> 2;
    const int n0 = (nt & 3) * 256;
    const ushortT* W = Wst + ((size_t)mat << 20);
    const float* bias = (mat == 0) ? b0 : (mat == 1) ? b1 : b2;
    ushortT* Out     = (mat == 0) ? O0 : (mat == 1) ? O1 : O2;

    const int w = t >> 6, lane = t & 63;
    const int wm = w >> 2, wn = w & 3;             // 2 x 4 wave grid
    const int col16 = lane & 15, quad = lane >> 4;
    const int c7 = col16 & 7;

    // fragment read offsets (elements); row&7 == col16&7 for all frag rows
    const int ko[2] = { ((0 + quad) ^ c7) << 3, ((4 + quad) ^ c7) << 3 };
    const int xbase = (wm * 128 + col16) * 64;     // x rows (MFMA B-operand)
    const int wbase = (wn * 64 + col16) * 64;      // W rows (MFMA A-operand)

    // staging: cid = q*512 + t -> row q*64+(t>>3), chunk t&7, sch = chunk^(row&7)
    const int trow = t >> 3;
    const int sch = (t & 7) ^ (trow & 7);
    const ushortT* gA[4]; const ushortT* gB[4];
    #pragma unroll
    for (int q = 0; q < 4; q++) {
        gA[q] = A + (size_t)(m0 + q * 64 + trow) * 1024 + sch * 8;
        gB[q] = W + (size_t)(n0 + q * 64 + trow) * 1024 + sch * 8;
    }
    const int dst0 = (w << 6) * 8;                 // wave-uniform LDS dest base

    floatx4 acc[8][4];
    #pragma unroll
    for (int i = 0; i < 8; i++)
        #pragma unroll
        for (int j = 0; j < 4; j++) acc[i][j] = (floatx4)0.0f;

    auto issue8 = [&](const int ab, const int bb) {
        #pragma unroll
        for (int q = 0; q < 4; q++) {
            gl_lds16(gA[q], sm + ab + dst0 + q * 4096);
            gl_lds16(gB[q], sm + bb + dst0 + q * 4096);
            gA[q] += 64; gB[q] += 64;
        }
    };

    auto group = [&](const int ab, const int bb) {   // 4 phases over one K-tile
        short8 bw[4];
        #pragma unroll
        for (int ks = 0; ks < 2; ks++) {
            #pragma unroll
            for (int mh = 0; mh < 2; mh++) {
                short8 bx[4];
                if (mh == 0) {
                    #pragma unroll
                    for (int nf = 0; nf < 4; nf++)
                        bw[nf] = *(const short8*)(sm + bb + wbase + nf * 1024 + ko[ks]);
                }
                #pragma unroll
                for (int j = 0; j < 4; j++)
                    bx[j] = *(const short8*)(sm + ab + xbase + (mh * 4 + j) * 1024 + ko[ks]);
                __builtin_amdgcn_s_barrier();
                __builtin_amdgcn_s_setprio(1);
                #pragma unroll
                for (int j = 0; j < 4; j++)
                    #pragma unroll
                    for (int nf = 0; nf < 4; nf++)
                        acc[mh * 4 + j][nf] = __builtin_amdgcn_mfma_f32_16x16x32_bf16(
                            bw[nf], bx[j], acc[mh * 4 + j][nf], 0, 0, 0);
                __builtin_amdgcn_s_setprio(0);
                __builtin_amdgcn_s_barrier();
            }
        }
    };

    issue8(0, 16384);            // tile 0 -> buf0
    issue8(32768, 49152);        // tile 1 -> buf1

    #pragma unroll 1
    for (int it = 0; it < 7; ++it) {
        asm volatile("s_waitcnt vmcnt(8)" ::: "memory");   // tile 2it landed
        __builtin_amdgcn_s_barrier();
        group(0, 16384);
        issue8(0, 16384);                                  // tile 2it+2 -> buf0
        asm volatile("s_waitcnt vmcnt(8)" ::: "memory");   // tile 2it+1 landed
        __builtin_amdgcn_s_barrier();
        group(32768, 49152);
        issue8(32768, 49152);                              // tile 2it+3 -> buf1
    }
    asm volatile("s_waitcnt vmcnt(8)" ::: "memory");       // tile 14 landed
    __builtin_amdgcn_s_barrier();
    group(0, 16384);
    asm volatile("s_waitcnt vmcnt(0)" ::: "memory");       // tile 15 landed
    __builtin_amdgcn_s_barrier();
    group(32768, 49152);

    // epilogue: D[n via quad*4+r, m via col16] (swapped-operand layout)
    #pragma unroll
    for (int mf = 0; mf < 8; mf++) {
        const int m = m0 + wm * 128 + mf * 16 + col16;
        #pragma unroll
        for (int nf = 0; nf < 4; nf++) {
            const int nb = n0 + wn * 64 + nf * 16 + quad * 4;
            const float4 bv4 = *(const float4*)(bias + nb);
            const float v0 = acc[mf][nf][0] + bv4.x;
            const float v1 = acc[mf][nf][1] + bv4.y;
            const float v2 = acc[mf][nf][2] + bv4.z;
            const float v3 = acc[mf][nf][3] + bv4.w;
            union { __hip_bfloat162 h[2]; unsigned long long u; } pk2;
            pk2.h[0] = __float22bfloat162_rn(float2{v0, v1});
            pk2.h[1] = __float22bfloat162_rn(float2{v2, v3});
            *(unsigned long long*)(Out + (size_t)m * 1024 + nb) = pk2.u;
        }
    }
}

// ---------------------------------------------------------------------------
// gemm_lds (out-proj only): C[m,n] = sum_k A[m,k]*W[n,k] + bias[n]. Tile
// 128 x 64, BK=64, 4 waves 2x2, MFMA operands swapped -> vectorized stores.
// ---------------------------------------------------------------------------
template <bool OUT_F32, bool N64>
__global__ __launch_bounds__(256) void gemm_lds(
    const ushortT* __restrict__ A, const ushortT* __restrict__ Wst,
    const float* __restrict__ b0, const float* __restrict__ b1, const float* __restrict__ b2,
    void* __restrict__ O0, void* __restrict__ O1, void* __restrict__ O2)
{
    constexpr int NT = N64 ? 64 : 128;
    constexpr int NJ = N64 ? 2 : 4;
    constexpr int WQ = N64 ? 2 : 4;
    __shared__ __align__(16) ushortT As[128 * 64];
    __shared__ __align__(16) ushortT Bs[NT * 64];
    const int t = threadIdx.x;
    const int m0 = blockIdx.y * 128;
    const int n0g = blockIdx.x * NT;
    const int mat = n0g >> 10;
    const int n0 = n0g & 1023;
    const ushortT* W = Wst + ((size_t)mat << 20);
    const float* bias = (mat == 0) ? b0 : (mat == 1) ? b1 : b2;
    void* Out        = (mat == 0) ? O0 : (mat == 1) ? O1 : O2;

    const int w = t >> 6, lane = t & 63;
    const int wm = w >> 1, wn = w & 1;
    const int col16 = lane & 15, quad = lane >> 4;

    floatx4 acc[4][NJ];
    for (int i = 0; i < 4; i++)
        for (int j = 0; j < NJ; j++) acc[i][j] = (floatx4)0.0f;

    const int cid0 = w * (N64 ? 128 : 256) + lane;

    for (int k0 = 0; k0 < 1024; k0 += 64) {
        #pragma unroll
        for (int q = 0; q < 4; q++) {
            const int cid = w * 256 + q * 64 + lane;
            const int row = cid >> 3;
            const int sch = (cid & 7) ^ (row & 7);
            gl_lds16(A + (size_t)(m0 + row) * 1024 + k0 + sch * 8,
                     As + (size_t)(w * 256 + q * 64) * 8);
        }
        #pragma unroll
        for (int q = 0; q < WQ; q++) {
            const int cid = cid0 + q * 64;
            const int row = cid >> 3;
            const int sch = (cid & 7) ^ (row & 7);
            gl_lds16(W + (size_t)(n0 + row) * 1024 + k0 + sch * 8,
                     Bs + (size_t)(w * (N64 ? 128 : 256) + q * 64) * 8);
        }
        __syncthreads();
        #pragma unroll
        for (int ks = 0; ks < 64; ks += 32) {
            const int cbase = (ks >> 3) + quad;
            const int sw = col16 & 7;
            short8 a[4], b[NJ];
            #pragma unroll
            for (int i = 0; i < 4; i++) {
                const int row = wm * 64 + i * 16 + col16;
                a[i] = *(const short8*)(As + row * 64 + ((cbase ^ sw) << 3));
            }
            #pragma unroll
            for (int j = 0; j < NJ; j++) {
                const int row = wn * (NT / 2) + j * 16 + col16;
                b[j] = *(const short8*)(Bs + row * 64 + ((cbase ^ sw) << 3));
            }
            #pragma unroll
            for (int i = 0; i < 4; i++)
                #pragma unroll
                for (int j = 0; j < NJ; j++)
                    acc[i][j] = __builtin_amdgcn_mfma_f32_16x16x32_bf16(b[j], a[i], acc[i][j], 0, 0, 0);
        }
        __syncthreads();
    }

    #pragma unroll
    for (int i = 0; i < 4; i++) {
        const int m = m0 + wm * 64 + i * 16 + col16;
        #pragma unroll
        for (int j = 0; j < NJ; j++) {
            const int nb = n0 + wn * (NT / 2) + j * 16 + quad * 4;
            const float4 bv4 = *(const float4*)(bias + nb);
            const float v0 = acc[i][j][0] + bv4.x;
            const float v1 = acc[i][j][1] + bv4.y;
            const float v2 = acc[i][j][2] + bv4.z;
            const float v3 = acc[i][j][3] + bv4.w;
            if constexpr (OUT_F32) {
                *(float4*)((float*)Out + (size_t)m * 1024 + nb) = float4{v0, v1, v2, v3};
            } else {
                union { __hip_bfloat162 h[2]; unsigned long long u; } pk2;
                pk2.h[0] = __float22bfloat162_rn(float2{v0, v1});
                pk2.h[1] = __float22bfloat162_rn(float2{v2, v3});
                *(unsigned long long*)((ushortT*)Out + (size_t)m * 1024 + nb) = pk2.u;
            }
        }
    }
}

// ---------------------------------------------------------------------------
// transpose_v: Vb (packed rows) -> VT[slice][d (64)][pos (2048)], slice=(b*2+g)*8+m'.
// ---------------------------------------------------------------------------
__global__ __launch_bounds__(256) void transpose_v(
    const ushortT* __restrict__ Vb, ushortT* __restrict__ VT)
{
    __shared__ ushortT L[64 * 65];
    const int bid = blockIdx.x;
    const int pt = bid & 31, s = bid >> 5;
    const int bb = s >> 4, g = (s >> 3) & 1, mh = s & 7;
    const size_t baseoff = (size_t)bb * 2048 * 1024 + (size_t)g * 512;
    const int t = threadIdx.x;
    {
        const int pr = t >> 2, seg = t & 3;
        const int i = mh * 2048 + pt * 64 + pr;
        const uint4* src = (const uint4*)(Vb + baseoff + (size_t)(i >> 3) * 1024 + (i & 7) * 64 + seg * 16);
        union { uint4 u[2]; ushortT h[16]; } tmp;
        tmp.u[0] = src[0]; tmp.u[1] = src[1];
        #pragma unroll
        for (int d = 0; d < 16; d++) L[pr * 65 + seg * 16 + d] = tmp.h[d];
    }
    __syncthreads();
    {
        const int dc = t >> 2, pseg = t & 3;
        union { uint4 u[2]; ushortT h[16]; } tmp;
        #pragma unroll
        for (int j = 0; j < 16; j++) tmp.h[j] = L[(pseg * 16 + j) * 65 + dc];
        uint4* dst = (uint4*)(VT + (size_t)s * 64 * 2048 + (size_t)dc * 2048 + pt * 64 + pseg * 16);
        dst[0] = tmp.u[0]; dst[1] = tmp.u[1];
    }
}

// ---------------------------------------------------------------------------
// attn v10: unified-LDS hoisted addressing, dbuf K/V, no-max softmax.
// ---------------------------------------------------------------------------
__global__ __launch_bounds__(256) void attn(
    const ushortT* __restrict__ Qb, const ushortT* __restrict__ Kb,
    const ushortT* __restrict__ VT, ushortT* __restrict__ Cb)
{
    __shared__ __align__(16) ushortT lds[20480];   // 40 KB

    const int t = threadIdx.x;
    const int bid = blockIdx.x;
    const int xcd = bid & 7;
    const int u = bid >> 3;
    const int s = xcd * 4 + (u & 3);
    const int x5 = u >> 2;
    const int qt = (x5 < 8) ? x5 : (x5 < 16) ? (39 - x5)
                 : (x5 < 24) ? (x5 - 8) : (47 - x5);   // CU-balanced bijection
    const int bb = s >> 4, g = (s >> 3) & 1, mh = s & 7;

    const int w = t >> 6, lane = t & 63;
    const int col16 = lane & 15, quad = lane >> 4;

    const size_t baseoff = (size_t)bb * 2048 * 1024 + (size_t)g * 512;
    const size_t vtbase  = (size_t)s * 64 * 2048;
    const int i0 = mh * 2048 + qt * 64;
    const int qloc = w * 16 + col16;
    const int c7 = col16 & 7;              // == qloc&7
    const float KL = 0.125f * 1.44269504f;

    // Q fragments in registers (B-operand layout)
    short8 qreg[2];
    {
        const int i = i0 + qloc;
        const ushortT* p = Qb + baseoff + (size_t)(i >> 3) * 1024 + (i & 7) * 64;
        qreg[0] = *(const short8*)(p + quad * 8);
        qreg[1] = *(const short8*)(p + 32 + quad * 8);
    }

    // hoisted read offsets (element units)
    int kbo[2];
    kbo[0] = col16 * 64 + (((0 + quad) ^ c7) << 3);
    kbo[1] = col16 * 64 + (((4 + quad) ^ c7) << 3);
    const int pso0 = 16384 + qloc * 64 + (((0 + quad) ^ c7) << 3);
    const int pso1 = 16384 + qloc * 64 + (((4 + quad) ^ c7) << 3);
    int pwo[4];
    #pragma unroll
    for (int c = 0; c < 4; c++) {
        const int key0 = c * 16 + quad * 4;
        pwo[c] = 16384 + qloc * 64 + ((((key0 >> 3) ^ c7)) << 3) + (key0 & 7);
    }

    // hoisted staging pointers (advance by constants per kt)
    const int cid0 = w * 128 + lane, cid1 = cid0 + 64;
    const int row0 = cid0 >> 3, sch0 = (cid0 & 7) ^ (row0 & 7);
    const int row1 = cid1 >> 3, sch1 = (cid1 & 7) ^ (row1 & 7);
    const int jr0 = mh * 2048 + row0;      // kt=0
    const int jr1 = mh * 2048 + row1;
    const ushortT* gk0 = Kb + baseoff + (size_t)(jr0 >> 3) * 1024 + (jr0 & 7) * 64 + sch0 * 8;
    const ushortT* gk1 = Kb + baseoff + (size_t)(jr1 >> 3) * 1024 + (jr1 & 7) * 64 + sch1 * 8;
    const ushortT* gv0 = VT + vtbase + (size_t)row0 * 2048 + sch0 * 8;
    const ushortT* gv1 = VT + vtbase + (size_t)row1 * 2048 + sch1 * 8;
    const int sdK = w * 1024;              // wave-uniform dest offset

    auto stage = [&](int sb) {
        gl_lds16(gk0, lds + sb + sdK);
        gl_lds16(gk1, lds + sb + sdK + 512);
        gl_lds16(gv0, lds + sb + 8192 + sdK);
        gl_lds16(gv1, lds + sb + 8192 + sdK + 512);
        gk0 += 8192; gk1 += 8192; gv0 += 64; gv1 += 64;
    };

    float l_s = 0.f;
    floatx4 Oacc[4];
    for (int c = 0; c < 4; c++) Oacc[c] = (floatx4)0.0f;

    stage(0);                              // prologue fills buffer 0
    int sb = 4096;                         // next stage target
    for (int kt = 0; kt <= qt; ++kt) {
        __syncthreads();                   // vmcnt drained -> read buffer ready
        if (kt < qt) { stage(sb); sb ^= 4096; }

        // S^T = K * Q^T
        floatx4 sc[4];
        for (int c = 0; c < 4; c++) sc[c] = (floatx4)0.0f;
        #pragma unroll
        for (int h = 0; h < 2; h++) {
            const short8 bq = qreg[h];
            #pragma unroll
            for (int c = 0; c < 4; c++) {
                const short8 ak = *(const short8*)(lds + kbo[h] + c * 1024);
                sc[c] = __builtin_amdgcn_mfma_f32_16x16x32_bf16(ak, bq, sc[c], 0, 0, 0);
            }
        }

        if (kt == qt) {                    // diagonal tile: causal mask
            #pragma unroll
            for (int c = 0; c < 4; c++)
                #pragma unroll
                for (int r = 0; r < 4; r++)
                    if ((c * 16 + quad * 4 + r) > qloc) sc[c][r] = -1e30f;
        }

        // no-max softmax: p = exp2(s*KL); per-lane l accumulation; Ps writes
        float lsum = l_s;
        #pragma unroll
        for (int c = 0; c < 4; c++) {
            #pragma unroll
            for (int r = 0; r < 4; r++) {
                const float pv = exp2f(sc[c][r] * KL);
                sc[c][r] = pv;
                lsum += pv;
            }
            union { __hip_bfloat162 h[2]; unsigned long long u; } pk2;
            pk2.h[0] = __float22bfloat162_rn(float2{sc[c][0], sc[c][1]});
            pk2.h[1] = __float22bfloat162_rn(float2{sc[c][2], sc[c][3]});
            *(unsigned long long*)(lds + pwo[c]) = pk2.u;
        }
        l_s = lsum;

        // O^T += V^T * P^T
        #pragma unroll
        for (int h = 0; h < 2; h++) {
            const short8 bp = *(const short8*)(lds + (h ? pso1 : pso0));
            #pragma unroll
            for (int c = 0; c < 4; c++) {
                const short8 av = *(const short8*)(lds + kbo[h] + 8192 + c * 1024);
                Oacc[c] = __builtin_amdgcn_mfma_f32_16x16x32_bf16(av, bp, Oacc[c], 0, 0, 0);
            }
        }

        kbo[0] ^= 4096; kbo[1] ^= 4096;    // flip read buffer
    }

    // cross-lane l reduce once (quads of same col16 hold same query)
    l_s += __shfl_xor(l_s, 16);
    l_s += __shfl_xor(l_s, 32);

    {
        const int i = i0 + qloc;
        const float inv = 1.0f / l_s;
        ushortT* dst = Cb + baseoff + (size_t)(i >> 3) * 1024 + (i & 7) * 64;
        #pragma unroll
        for (int c = 0; c < 4; c++) {
            union { __hip_bfloat162 h[2]; unsigned long long u; } pk2;
            pk2.h[0] = __float22bfloat162_rn(float2{Oacc[c][0] * inv, Oacc[c][1] * inv});
            pk2.h[1] = __float22bfloat162_rn(float2{Oacc[c][2] * inv, Oacc[c][3] * inv});
            *(unsigned long long*)(dst + c * 16 + quad * 4) = pk2.u;
        }
    }
}

extern "C" void kernel_launch(void* const* d_in, const int* in_sizes, int n_in,
                              void* d_out, int out_size, void* d_ws, size_t ws_size,
                              hipStream_t stream)
{
    const float* x  = (const float*)d_in[0];
    const float* Wq = (const float*)d_in[1];
    const float* bq = (const float*)d_in[2];
    const float* Wk = (const float*)d_in[3];
    const float* bk = (const float*)d_in[4];
    const float* Wv = (const float*)d_in[5];
    const float* bv = (const float*)d_in[6];
    const float* Wo = (const float*)d_in[7];
    const float* bo = (const float*)d_in[8];

    const size_t M1 = (size_t)1024 * 1024;
    ushortT* Wb  = (ushortT*)d_ws;            // Wq|Wk|Wv|Wo bf16, 8 MB
    ushortT* xb  = Wb + 4 * M1;               // 8 MB; reused as VT after QKV
    ushortT* Qb  = xb + 4 * M1;               // 8 MB; reused as Cb
    ushortT* Kb  = Qb + 4 * M1;               // 8 MB
    ushortT* Vb  = (ushortT*)d_out;           // V scratch in output buffer
    ushortT* VTb = xb;
    ushortT* Cb  = Qb;

    dim3 blk(256);
    cvt_bf16<<<dim3(4096), blk, 0, stream>>>(x, Wq, Wk, Wv, Wo, xb, Wb);
    gemm_qkv_8p<<<dim3(192), dim3(512), 0, stream>>>(
        xb, Wb, bq, bk, bv, Qb, Kb, Vb);
    transpose_v<<<dim3(1024), blk, 0, stream>>>(Vb, VTb);
    attn<<<dim3(1024), blk, 0, stream>>>(Qb, Kb, VTb, Cb);
    gemm_lds<true, true><<<dim3(16, 32), blk, 0, stream>>>(
        Cb, Wb + 3 * M1, bo, bo, bo, d_out, d_out, d_out);
}

// Round 2
// 183.973 us; speedup vs baseline: 1.0767x; 1.0473x over previous
//
#include <hip/hip_runtime.h>
#include <hip/hip_bf16.h>

// MicroHeadAttention on MI355X (gfx950). fp32 in / fp32 out, bf16 MFMA internally.
// Pipeline: [cvt fp32->bf16] -> [QKV gemm 256x256 8-phase, Q pre-scaled by KL]
//        -> [transpose_v] -> [attn v11: register-P softmax via permlane swaps]
//        -> [out-proj gemm 128x64].
// Packed index i = n*8 + m per (b,g): scrambled head m'=i>>11, pos = i&2047.
// Address of packed row i: (b*2048 + (i>>3))*1024 + g*512 + (i&7)*64.
// Workspace (32 MB): Wb(8) | xb(8, reused as VT) | Qb(8, reused as Cb) | Kb(8).
// V uses d_out as scratch (dead before out-proj overwrites d_out).

typedef unsigned short ushortT;
typedef __attribute__((ext_vector_type(8))) short short8;
typedef __attribute__((ext_vector_type(4))) float floatx4;
typedef __attribute__((ext_vector_type(2))) unsigned int uintx2;

__device__ inline void gl_lds16(const ushortT* g, ushortT* lds) {
    __builtin_amdgcn_global_load_lds(
        (const __attribute__((address_space(1))) unsigned int*)g,
        (__attribute__((address_space(3))) unsigned int*)lds, 16, 0, 0);
}

// ---------------------------------------------------------------------------
// cvt: x (4M f32) -> xb bf16; Wq,Wk,Wv,Wo (1M each) -> Wb stacked bf16.
// ---------------------------------------------------------------------------
__global__ __launch_bounds__(256) void cvt_bf16(
    const float* __restrict__ x,
    const float* __restrict__ Wq, const float* __restrict__ Wk,
    const float* __restrict__ Wv, const float* __restrict__ Wo,
    ushortT* __restrict__ xb, ushortT* __restrict__ Wb)
{
    const unsigned tid = blockIdx.x * 256 + threadIdx.x;
    const size_t e = (size_t)tid * 8;
    const float* src;
    ushortT* dst;
    size_t off;
    if (e < (size_t)(4u << 20)) { src = x; dst = xb; off = e; }
    else {
        const size_t r = e - (size_t)(4u << 20);
        const int wsel = (int)(r >> 20);
        off = r & 0xFFFFFu;
        src = (wsel == 0) ? Wq : (wsel == 1) ? Wk : (wsel == 2) ? Wv : Wo;
        dst = Wb + ((size_t)wsel << 20);
    }
    const float4 f0 = ((const float4*)(src + off))[0];
    const float4 f1 = ((const float4*)(src + off))[1];
    union { __hip_bfloat162 h[4]; uint4 u; } pk;
    pk.h[0] = __float22bfloat162_rn(float2{f0.x, f0.y});
    pk.h[1] = __float22bfloat162_rn(float2{f0.z, f0.w});
    pk.h[2] = __float22bfloat162_rn(float2{f1.x, f1.y});
    pk.h[3] = __float22bfloat162_rn(float2{f1.z, f1.w});
    *(uint4*)(dst + off) = pk.u;
}

// ---------------------------------------------------------------------------
// gemm_qkv_8p: C[m,n] = (sum_k A[m,k]*W[n,k] + bias[n]) * oscale, bf16 out.
// oscale = softmax KL scale for the Q matrix (mat 0), 1.0 for K/V.
// 256x256 tile, BK=64, 512 thr (8 waves 2Mx4N, 128x64 per wave), 16 K-tiles.
// T3+T4+T5 schedule: raw s_barrier + counted vmcnt(8) + setprio.
// 128 KB LDS: A0|B0|A1|B1 (16384 elts each), XOR chunk swizzle.
// ---------------------------------------------------------------------------
__global__ __launch_bounds__(512, 2) void gemm_qkv_8p(
    const ushortT* __restrict__ A, const ushortT* __restrict__ Wst,
    const float* __restrict__ b0, const float* __restrict__ b1, const float* __restrict__ b2,
    ushortT* __restrict__ O0, ushortT* __restrict__ O1, ushortT* __restrict__ O2)
{
    __shared__ __align__(16) ushortT sm[65536];   // 128 KB

    const int t = threadIdx.x;
    const int bid = blockIdx.x;                    // 0..191
    const int wg = (bid & 7) * 24 + (bid >> 3);    // bijective XCD chunk swizzle
    const int mt = wg / 12;                        // 0..15
    const int nt = wg - mt * 12;                   // 0..11 (3 mats x 4 tiles)
    const int m0 = mt * 256;
    const int mat = nt >> 2;
    const int n0 = (nt & 3) * 256;
    const ushortT* W = Wst + ((size_t)mat << 20);
    const float* bias = (mat == 0) ? b0 : (mat == 1) ? b1 : b2;
    ushortT* Out     = (mat == 0) ? O0 : (mat == 1) ? O1 : O2;
    const float oscale = (mat == 0) ? 0.18033688f : 1.0f;   // 0.125*log2(e)

    const int w = t >> 6, lane = t & 63;
    const int wm = w >> 2, wn = w & 3;             // 2 x 4 wave grid
    const int col16 = lane & 15, quad = lane >> 4;
    const int c7 = col16 & 7;

    // fragment read offsets (elements); row&7 == col16&7 for all frag rows
    const int ko[2] = { ((0 + quad) ^ c7) << 3, ((4 + quad) ^ c7) << 3 };
    const int xbase = (wm * 128 + col16) * 64;     // x rows (MFMA B-operand)
    const int wbase = (wn * 64 + col16) * 64;      // W rows (MFMA A-operand)

    // staging: cid = q*512 + t -> row q*64+(t>>3), chunk t&7, sch = chunk^(row&7)
    const int trow = t >> 3;
    const int sch = (t & 7) ^ (trow & 7);
    const ushortT* gA[4]; const ushortT* gB[4];
    #pragma unroll
    for (int q = 0; q < 4; q++) {
        gA[q] = A + (size_t)(m0 + q * 64 + trow) * 1024 + sch * 8;
        gB[q] = W + (size_t)(n0 + q * 64 + trow) * 1024 + sch * 8;
    }
    const int dst0 = (w << 6) * 8;                 // wave-uniform LDS dest base

    floatx4 acc[8][4];
    #pragma unroll
    for (int i = 0; i < 8; i++)
        #pragma unroll
        for (int j = 0; j < 4; j++) acc[i][j] = (floatx4)0.0f;

    auto issue8 = [&](const int ab, const int bb) {
        #pragma unroll
        for (int q = 0; q < 4; q++) {
            gl_lds16(gA[q], sm + ab + dst0 + q * 4096);
            gl_lds16(gB[q], sm + bb + dst0 + q * 4096);
            gA[q] += 64; gB[q] += 64;
        }
    };

    auto group = [&](const int ab, const int bb) {   // 4 phases over one K-tile
        short8 bw[4];
        #pragma unroll
        for (int ks = 0; ks < 2; ks++) {
            #pragma unroll
            for (int mh = 0; mh < 2; mh++) {
                short8 bx[4];
                if (mh == 0) {
                    #pragma unroll
                    for (int nf = 0; nf < 4; nf++)
                        bw[nf] = *(const short8*)(sm + bb + wbase + nf * 1024 + ko[ks]);
                }
                #pragma unroll
                for (int j = 0; j < 4; j++)
                    bx[j] = *(const short8*)(sm + ab + xbase + (mh * 4 + j) * 1024 + ko[ks]);
                __builtin_amdgcn_s_barrier();
                __builtin_amdgcn_s_setprio(1);
                #pragma unroll
                for (int j = 0; j < 4; j++)
                    #pragma unroll
                    for (int nf = 0; nf < 4; nf++)
                        acc[mh * 4 + j][nf] = __builtin_amdgcn_mfma_f32_16x16x32_bf16(
                            bw[nf], bx[j], acc[mh * 4 + j][nf], 0, 0, 0);
                __builtin_amdgcn_s_setprio(0);
                __builtin_amdgcn_s_barrier();
            }
        }
    };

    issue8(0, 16384);            // tile 0 -> buf0
    issue8(32768, 49152);        // tile 1 -> buf1

    #pragma unroll 1
    for (int it = 0; it < 7; ++it) {
        asm volatile("s_waitcnt vmcnt(8)" ::: "memory");   // tile 2it landed
        __builtin_amdgcn_s_barrier();
        group(0, 16384);
        issue8(0, 16384);                                  // tile 2it+2 -> buf0
        asm volatile("s_waitcnt vmcnt(8)" ::: "memory");   // tile 2it+1 landed
        __builtin_amdgcn_s_barrier();
        group(32768, 49152);
        issue8(32768, 49152);                              // tile 2it+3 -> buf1
    }
    asm volatile("s_waitcnt vmcnt(8)" ::: "memory");       // tile 14 landed
    __builtin_amdgcn_s_barrier();
    group(0, 16384);
    asm volatile("s_waitcnt vmcnt(0)" ::: "memory");       // tile 15 landed
    __builtin_amdgcn_s_barrier();
    group(32768, 49152);

    // epilogue: D[n via quad*4+r, m via col16] (swapped-operand layout)
    #pragma unroll
    for (int mf = 0; mf < 8; mf++) {
        const int m = m0 + wm * 128 + mf * 16 + col16;
        #pragma unroll
        for (int nf = 0; nf < 4; nf++) {
            const int nb = n0 + wn * 64 + nf * 16 + quad * 4;
            const float4 bv4 = *(const float4*)(bias + nb);
            const float v0 = (acc[mf][nf][0] + bv4.x) * oscale;
            const float v1 = (acc[mf][nf][1] + bv4.y) * oscale;
            const float v2 = (acc[mf][nf][2] + bv4.z) * oscale;
            const float v3 = (acc[mf][nf][3] + bv4.w) * oscale;
            union { __hip_bfloat162 h[2]; unsigned long long u; } pk2;
            pk2.h[0] = __float22bfloat162_rn(float2{v0, v1});
            pk2.h[1] = __float22bfloat162_rn(float2{v2, v3});
            *(unsigned long long*)(Out + (size_t)m * 1024 + nb) = pk2.u;
        }
    }
}

// ---------------------------------------------------------------------------
// gemm_lds (out-proj only): C[m,n] = sum_k A[m,k]*W[n,k] + bias[n]. Tile
// 128 x 64, BK=64, 4 waves 2x2, MFMA operands swapped -> vectorized stores.
// ---------------------------------------------------------------------------
template <bool OUT_F32, bool N64>
__global__ __launch_bounds__(256) void gemm_lds(
    const ushortT* __restrict__ A, const ushortT* __restrict__ Wst,
    const float* __restrict__ b0, const float* __restrict__ b1, const float* __restrict__ b2,
    void* __restrict__ O0, void* __restrict__ O1, void* __restrict__ O2)
{
    constexpr int NT = N64 ? 64 : 128;
    constexpr int NJ = N64 ? 2 : 4;
    constexpr int WQ = N64 ? 2 : 4;
    __shared__ __align__(16) ushortT As[128 * 64];
    __shared__ __align__(16) ushortT Bs[NT * 64];
    const int t = threadIdx.x;
    const int m0 = blockIdx.y * 128;
    const int n0g = blockIdx.x * NT;
    const int mat = n0g >> 10;
    const int n0 = n0g & 1023;
    const ushortT* W = Wst + ((size_t)mat << 20);
    const float* bias = (mat == 0) ? b0 : (mat == 1) ? b1 : b2;
    void* Out        = (mat == 0) ? O0 : (mat == 1) ? O1 : O2;

    const int w = t >> 6, lane = t & 63;
    const int wm = w >> 1, wn = w & 1;
    const int col16 = lane & 15, quad = lane >> 4;

    floatx4 acc[4][NJ];
    for (int i = 0; i < 4; i++)
        for (int j = 0; j < NJ; j++) acc[i][j] = (floatx4)0.0f;

    const int cid0 = w * (N64 ? 128 : 256) + lane;

    for (int k0 = 0; k0 < 1024; k0 += 64) {
        #pragma unroll
        for (int q = 0; q < 4; q++) {
            const int cid = w * 256 + q * 64 + lane;
            const int row = cid >> 3;
            const int sch = (cid & 7) ^ (row & 7);
            gl_lds16(A + (size_t)(m0 + row) * 1024 + k0 + sch * 8,
                     As + (size_t)(w * 256 + q * 64) * 8);
        }
        #pragma unroll
        for (int q = 0; q < WQ; q++) {
            const int cid = cid0 + q * 64;
            const int row = cid >> 3;
            const int sch = (cid & 7) ^ (row & 7);
            gl_lds16(W + (size_t)(n0 + row) * 1024 + k0 + sch * 8,
                     Bs + (size_t)(w * (N64 ? 128 : 256) + q * 64) * 8);
        }
        __syncthreads();
        #pragma unroll
        for (int ks = 0; ks < 64; ks += 32) {
            const int cbase = (ks >> 3) + quad;
            const int sw = col16 & 7;
            short8 a[4], b[NJ];
            #pragma unroll
            for (int i = 0; i < 4; i++) {
                const int row = wm * 64 + i * 16 + col16;
                a[i] = *(const short8*)(As + row * 64 + ((cbase ^ sw) << 3));
            }
            #pragma unroll
            for (int j = 0; j < NJ; j++) {
                const int row = wn * (NT / 2) + j * 16 + col16;
                b[j] = *(const short8*)(Bs + row * 64 + ((cbase ^ sw) << 3));
            }
            #pragma unroll
            for (int i = 0; i < 4; i++)
                #pragma unroll
                for (int j = 0; j < NJ; j++)
                    acc[i][j] = __builtin_amdgcn_mfma_f32_16x16x32_bf16(b[j], a[i], acc[i][j], 0, 0, 0);
        }
        __syncthreads();
    }

    #pragma unroll
    for (int i = 0; i < 4; i++) {
        const int m = m0 + wm * 64 + i * 16 + col16;
        #pragma unroll
        for (int j = 0; j < NJ; j++) {
            const int nb = n0 + wn * (NT / 2) + j * 16 + quad * 4;
            const float4 bv4 = *(const float4*)(bias + nb);
            const float v0 = acc[i][j][0] + bv4.x;
            const float v1 = acc[i][j][1] + bv4.y;
            const float v2 = acc[i][j][2] + bv4.z;
            const float v3 = acc[i][j][3] + bv4.w;
            if constexpr (OUT_F32) {
                *(float4*)((float*)Out + (size_t)m * 1024 + nb) = float4{v0, v1, v2, v3};
            } else {
                union { __hip_bfloat162 h[2]; unsigned long long u; } pk2;
                pk2.h[0] = __float22bfloat162_rn(float2{v0, v1});
                pk2.h[1] = __float22bfloat162_rn(float2{v2, v3});
                *(unsigned long long*)((ushortT*)Out + (size_t)m * 1024 + nb) = pk2.u;
            }
        }
    }
}

// ---------------------------------------------------------------------------
// transpose_v: Vb (packed rows) -> VT[slice][d (64)][pos (2048)], slice=(b*2+g)*8+m'.
// ---------------------------------------------------------------------------
__global__ __launch_bounds__(256) void transpose_v(
    const ushortT* __restrict__ Vb, ushortT* __restrict__ VT)
{
    __shared__ ushortT L[64 * 65];
    const int bid = blockIdx.x;
    const int pt = bid & 31, s = bid >> 5;
    const int bb = s >> 4, g = (s >> 3) & 1, mh = s & 7;
    const size_t baseoff = (size_t)bb * 2048 * 1024 + (size_t)g * 512;
    const int t = threadIdx.x;
    {
        const int pr = t >> 2, seg = t & 3;
        const int i = mh * 2048 + pt * 64 + pr;
        const uint4* src = (const uint4*)(Vb + baseoff + (size_t)(i >> 3) * 1024 + (i & 7) * 64 + seg * 16);
        union { uint4 u[2]; ushortT h[16]; } tmp;
        tmp.u[0] = src[0]; tmp.u[1] = src[1];
        #pragma unroll
        for (int d = 0; d < 16; d++) L[pr * 65 + seg * 16 + d] = tmp.h[d];
    }
    __syncthreads();
    {
        const int dc = t >> 2, pseg = t & 3;
        union { uint4 u[2]; ushortT h[16]; } tmp;
        #pragma unroll
        for (int j = 0; j < 16; j++) tmp.h[j] = L[(pseg * 16 + j) * 65 + dc];
        uint4* dst = (uint4*)(VT + (size_t)s * 64 * 2048 + (size_t)dc * 2048 + pt * 64 + pseg * 16);
        dst[0] = tmp.u[0]; dst[1] = tmp.u[1];
    }
}

// ---------------------------------------------------------------------------
// attn v11: register-P softmax. Q pre-scaled by KL in QKV gemm.
// LDS 32 KB: K dbuf @0/@4096, V dbuf @8192/@12288 (elements).
//   K frag(c,h) = kbo[h] + c*1024; V frag(c,h) = kbo[h] + 8192 + c*1024.
// Softmax: pv = v_exp_f32(sc) (single instr), 4 independent l accumulators.
// P redistribution for the PV B-operand is done fully in registers:
//   source lane (q=col16, quad S) holds P pair-index 8c+2S+u in pw[c][u];
//   target lane (q, quad Q) needs pair 16h+4Q+i. With A=pw[2h][u],
//   B=pw[2h+1][u]: permlane32_swap -> ([A0,A1,B0,B1],[A2,A3,B2,B3]);
//   permlane16_swap of those -> ([A0,A2,B0,B2],[A1,A3,B1,B3]) which are the
//   i=u and i=2+u dwords of the B fragment. 8 cvt_pk + 8 permlane replace
//   4 ds_write_b64 + 2 ds_read_b128 + lgkm wait + bank conflicts.
// ---------------------------------------------------------------------------
__global__ __launch_bounds__(256) void attn(
    const ushortT* __restrict__ Qb, const ushortT* __restrict__ Kb,
    const ushortT* __restrict__ VT, ushortT* __restrict__ Cb)
{
    __shared__ __align__(16) ushortT lds[16384];   // 32 KB

    const int t = threadIdx.x;
    const int bid = blockIdx.x;
    const int xcd = bid & 7;
    const int u = bid >> 3;
    const int s = xcd * 4 + (u & 3);
    const int x5 = u >> 2;
    const int qt = (x5 < 8) ? x5 : (x5 < 16) ? (39 - x5)
                 : (x5 < 24) ? (x5 - 8) : (47 - x5);   // CU-balanced bijection
    const int bb = s >> 4, g = (s >> 3) & 1, mh = s & 7;

    const int w = t >> 6, lane = t & 63;
    const int col16 = lane & 15, quad = lane >> 4;

    const size_t baseoff = (size_t)bb * 2048 * 1024 + (size_t)g * 512;
    const size_t vtbase  = (size_t)s * 64 * 2048;
    const int i0 = mh * 2048 + qt * 64;
    const int qloc = w * 16 + col16;
    const int c7 = col16 & 7;              // == qloc&7

    // Q fragments in registers (B-operand layout); Q pre-scaled by KL
    short8 qreg[2];
    {
        const int i = i0 + qloc;
        const ushortT* p = Qb + baseoff + (size_t)(i >> 3) * 1024 + (i & 7) * 64;
        qreg[0] = *(const short8*)(p + quad * 8);
        qreg[1] = *(const short8*)(p + 32 + quad * 8);
    }

    // hoisted K/V read offsets (element units)
    int kbo[2];
    kbo[0] = col16 * 64 + (((0 + quad) ^ c7) << 3);
    kbo[1] = col16 * 64 + (((4 + quad) ^ c7) << 3);

    // hoisted staging pointers (advance by constants per kt)
    const int cid0 = w * 128 + lane, cid1 = cid0 + 64;
    const int row0 = cid0 >> 3, sch0 = (cid0 & 7) ^ (row0 & 7);
    const int row1 = cid1 >> 3, sch1 = (cid1 & 7) ^ (row1 & 7);
    const int jr0 = mh * 2048 + row0;      // kt=0
    const int jr1 = mh * 2048 + row1;
    const ushortT* gk0 = Kb + baseoff + (size_t)(jr0 >> 3) * 1024 + (jr0 & 7) * 64 + sch0 * 8;
    const ushortT* gk1 = Kb + baseoff + (size_t)(jr1 >> 3) * 1024 + (jr1 & 7) * 64 + sch1 * 8;
    const ushortT* gv0 = VT + vtbase + (size_t)row0 * 2048 + sch0 * 8;
    const ushortT* gv1 = VT + vtbase + (size_t)row1 * 2048 + sch1 * 8;
    const int sdK = w * 1024;              // wave-uniform dest offset

    auto stage = [&](int sb) {
        gl_lds16(gk0, lds + sb + sdK);
        gl_lds16(gk1, lds + sb + sdK + 512);
        gl_lds16(gv0, lds + sb + 8192 + sdK);
        gl_lds16(gv1, lds + sb + 8192 + sdK + 512);
        gk0 += 8192; gk1 += 8192; gv0 += 64; gv1 += 64;
    };

    float l4[4] = {0.f, 0.f, 0.f, 0.f};
    floatx4 Oacc[4];
    for (int c = 0; c < 4; c++) Oacc[c] = (floatx4)0.0f;

    stage(0);                              // prologue fills buffer 0
    int sb = 4096;                         // next stage target
    for (int kt = 0; kt <= qt; ++kt) {
        __syncthreads();                   // vmcnt drained -> read buffer ready
        if (kt < qt) { stage(sb); sb ^= 4096; }

        // S^T = K * Q^T (Q carries the KL scale already)
        floatx4 sc[4];
        for (int c = 0; c < 4; c++) sc[c] = (floatx4)0.0f;
        #pragma unroll
        for (int h = 0; h < 2; h++) {
            const short8 bq = qreg[h];
            #pragma unroll
            for (int c = 0; c < 4; c++) {
                const short8 ak = *(const short8*)(lds + kbo[h] + c * 1024);
                sc[c] = __builtin_amdgcn_mfma_f32_16x16x32_bf16(ak, bq, sc[c], 0, 0, 0);
            }
        }

        if (kt == qt) {                    // diagonal tile: causal mask
            #pragma unroll
            for (int c = 0; c < 4; c++)
                #pragma unroll
                for (int r = 0; r < 4; r++)
                    if ((c * 16 + quad * 4 + r) > qloc) sc[c][r] = -1e30f;
        }

        // no-max softmax: p = exp2(s); independent l chains; pack to bf16 pairs
        unsigned pw[4][2];
        #pragma unroll
        for (int c = 0; c < 4; c++) {
            float pv0 = __builtin_amdgcn_exp2f(sc[c][0]);
            float pv1 = __builtin_amdgcn_exp2f(sc[c][1]);
            float pv2 = __builtin_amdgcn_exp2f(sc[c][2]);
            float pv3 = __builtin_amdgcn_exp2f(sc[c][3]);
            l4[0] += pv0; l4[1] += pv1; l4[2] += pv2; l4[3] += pv3;
            union { __hip_bfloat162 h; unsigned u; } a, b;
            a.h = __float22bfloat162_rn(float2{pv0, pv1});
            b.h = __float22bfloat162_rn(float2{pv2, pv3});
            pw[c][0] = a.u; pw[c][1] = b.u;
        }

        // O^T += V^T * P^T; P^T B-frags built via permlane swaps
        #pragma unroll
        for (int h = 0; h < 2; h++) {
            unsigned dw[4];
            #pragma unroll
            for (int uu = 0; uu < 2; uu++) {
                uintx2 s32 = __builtin_amdgcn_permlane32_swap(pw[2 * h][uu], pw[2 * h + 1][uu], false, false);
                uintx2 s16 = __builtin_amdgcn_permlane16_swap(s32.x, s32.y, false, false);
                dw[uu] = s16.x; dw[2 + uu] = s16.y;
            }
            union { unsigned u[4]; short8 s; } bpu;
            bpu.u[0] = dw[0]; bpu.u[1] = dw[1]; bpu.u[2] = dw[2]; bpu.u[3] = dw[3];
            const short8 bp = bpu.s;
            #pragma unroll
            for (int c = 0; c < 4; c++) {
                const short8 av = *(const short8*)(lds + kbo[h] + 8192 + c * 1024);
                Oacc[c] = __builtin_amdgcn_mfma_f32_16x16x32_bf16(av, bp, Oacc[c], 0, 0, 0);
            }
        }

        kbo[0] ^= 4096; kbo[1] ^= 4096;    // flip read buffer
    }

    // combine l chains, then cross-lane reduce (quads of same col16 = same query)
    float l_s = (l4[0] + l4[1]) + (l4[2] + l4[3]);
    l_s += __shfl_xor(l_s, 16);
    l_s += __shfl_xor(l_s, 32);

    {
        const int i = i0 + qloc;
        const float inv = 1.0f / l_s;
        ushortT* dst = Cb + baseoff + (size_t)(i >> 3) * 1024 + (i & 7) * 64;
        #pragma unroll
        for (int c = 0; c < 4; c++) {
            union { __hip_bfloat162 h[2]; unsigned long long u; } pk2;
            pk2.h[0] = __float22bfloat162_rn(float2{Oacc[c][0] * inv, Oacc[c][1] * inv});
            pk2.h[1] = __float22bfloat162_rn(float2{Oacc[c][2] * inv, Oacc[c][3] * inv});
            *(unsigned long long*)(dst + c * 16 + quad * 4) = pk2.u;
        }
    }
}

extern "C" void kernel_launch(void* const* d_in, const int* in_sizes, int n_in,
                              void* d_out, int out_size, void* d_ws, size_t ws_size,
                              hipStream_t stream)
{
    const float* x  = (const float*)d_in[0];
    const float* Wq = (const float*)d_in[1];
    const float* bq = (const float*)d_in[2];
    const float* Wk = (const float*)d_in[3];
    const float* bk = (const float*)d_in[4];
    const float* Wv = (const float*)d_in[5];
    const float* bv = (const float*)d_in[6];
    const float* Wo = (const float*)d_in[7];
    const float* bo = (const float*)d_in[8];

    const size_t M1 = (size_t)1024 * 1024;
    ushortT* Wb  = (ushortT*)d_ws;            // Wq|Wk|Wv|Wo bf16, 8 MB
    ushortT* xb  = Wb + 4 * M1;               // 8 MB; reused as VT after QKV
    ushortT* Qb  = xb + 4 * M1;               // 8 MB; reused as Cb
    ushortT* Kb  = Qb + 4 * M1;               // 8 MB
    ushortT* Vb  = (ushortT*)d_out;           // V scratch in output buffer
    ushortT* VTb = xb;
    ushortT* Cb  = Qb;

    dim3 blk(256);
    cvt_bf16<<<dim3(4096), blk, 0, stream>>>(x, Wq, Wk, Wv, Wo, xb, Wb);
    gemm_qkv_8p<<<dim3(192), dim3(512), 0, stream>>>(
        xb, Wb, bq, bk, bv, Qb, Kb, Vb);
    transpose_v<<<dim3(1024), blk, 0, stream>>>(Vb, VTb);
    attn<<<dim3(1024), blk, 0, stream>>>(Qb, Kb, VTb, Cb);
    gemm_lds<true, true><<<dim3(16, 32), blk, 0, stream>>>(
        Cb, Wb + 3 * M1, bo, bo, bo, d_out, d_out, d_out);
}